// Round 1
// baseline (43875.903 us; speedup 1.0000x reference)
//
#include <hip/hip_runtime.h>
#include <hip/hip_cooperative_groups.h>

namespace cg = cooperative_groups;

// T=512, B=32, I=512, H=512, bidirectional GRU, fp32.
// One persistent cooperative kernel. 256 blocks = 2 dirs x 128 slices
// (each slice owns 4 h-indices). 512 threads/block:
//   tid = [bgh(1) | jj(2) | bglow(2) | q(4)]
//   q     = K-sixteenth (each thread covers 32 of the 512 K elems)
//   jj    = which of the 4 h-indices of the slice (uniform per wave)
//   bg    = bgh*4+bglow -> 4 batch rows b0..b0+3 per thread (weight reuse x4)
// Weights (24 rows x 512) live in LDS; h-state is exchanged through the
// output buffer y (y[t] IS h_t), one grid.sync() per timestep.

constexpr int T_ = 512, B_ = 32, I_ = 512, H_ = 512;
constexpr int NBLK = 256;
constexpr int NTHR = 512;
constexpr int ROW_F4 = 128;          // 512 floats per LDS row

__device__ __forceinline__ float sigmoid_(float v) {
    return 1.0f / (1.0f + __expf(-v));
}
__device__ __forceinline__ float tanh_(float v) {
    v = fminf(fmaxf(v, -15.0f), 15.0f);   // tanh saturates; avoid exp overflow
    float e = __expf(2.0f * v);
    return (e - 1.0f) / (e + 1.0f);
}

__global__ __launch_bounds__(NTHR, 1) void gru_bidir(
    const float* __restrict__ x, const float* __restrict__ h0,
    const float* __restrict__ w_ih, const float* __restrict__ w_hh,
    const float* __restrict__ b_ih, const float* __restrict__ b_hh,
    float* __restrict__ out)
{
    cg::grid_group grid = cg::this_grid();
    extern __shared__ float lds[];           // 24 rows x 512 floats = 48 KiB
    float4* lds4 = (float4*)lds;

    const int bid = blockIdx.x;
    const int d   = bid >> 7;                // direction 0=fwd, 1=bwd
    const int s   = bid & 127;               // h-slice: indices [4s, 4s+4)
    const int tid = threadIdx.x;

    // ---- stage the block's 24 weight rows into LDS (one-time) ----
    // row = m*4 + jj ; m: 0..2 = w_ih r,z,n ; 3..5 = w_hh r,z,n
    for (int idx = tid; idx < 24 * ROW_F4; idx += NTHR) {
        const int row = idx >> 7;
        const int f4p = idx & 127;
        const int m   = row >> 2, jjr = row & 3;
        const int g   = (m < 3) ? m : m - 3;
        const float* W = (m < 3) ? w_ih : w_hh;
        const float4* src =
            (const float4*)(W + ((size_t)d * (3 * H_) + g * H_ + s * 4 + jjr) * (size_t)I_);
        lds4[row * ROW_F4 + f4p] = src[f4p];
    }
    __syncthreads();

    const int q     = tid & 15;
    const int bglow = (tid >> 4) & 3;
    const int upper = tid >> 6;
    const int jj    = upper & 3;             // uniform within a wave
    const int bgh   = upper >> 2;
    const int b0    = bgh * 16 + bglow * 4;  // this thread's 4 batch rows
    const int j     = s * 4 + jj;            // output h-index

    const float bihr = b_ih[d * 1536 + j];
    const float bihz = b_ih[d * 1536 + 512 + j];
    const float bihn = b_ih[d * 1536 + 1024 + j];
    const float bhhr = b_hh[d * 1536 + j];
    const float bhhz = b_hh[d * 1536 + 512 + j];
    const float bhhn = b_hh[d * 1536 + 1024 + j];

    // per-wave weight row bases; within-wave addresses vary only with q
    // (16 unique 16B addrs, broadcast over bglow) -> ~conflict-free ds_read_b128
    const float4* wri = lds4 + (0 * 4 + jj) * ROW_F4 + q;
    const float4* wzi = lds4 + (1 * 4 + jj) * ROW_F4 + q;
    const float4* wni = lds4 + (2 * 4 + jj) * ROW_F4 + q;
    const float4* wrh = lds4 + (3 * 4 + jj) * ROW_F4 + q;
    const float4* wzh = lds4 + (4 * 4 + jj) * ROW_F4 + q;
    const float4* wnh = lds4 + (5 * 4 + jj) * ROW_F4 + q;

    for (int k = 0; k < T_; ++k) {
        const int t = d ? (T_ - 1 - k) : k;
        const float* hbase;
        int hstride, hoff;
        if (k == 0) {
            hbase = h0 + (size_t)d * B_ * H_; hstride = H_; hoff = 0;
        } else {
            const int tp = d ? (t + 1) : (t - 1);
            hbase = out + (size_t)tp * B_ * (2 * H_); hstride = 2 * H_; hoff = d * H_;
        }

        float air[4], aiz[4], ain[4], ahr[4], ahz[4], ahn[4];
#pragma unroll
        for (int bi = 0; bi < 4; ++bi) {
            air[bi] = 0.f; aiz[bi] = 0.f; ain[bi] = 0.f;
            ahr[bi] = 0.f; ahz[bi] = 0.f; ahn[bi] = 0.f;
        }

        const float4* xr[4];
        const float4* hr[4];
#pragma unroll
        for (int bi = 0; bi < 4; ++bi) {
            xr[bi] = (const float4*)(x + ((size_t)t * B_ + (b0 + bi)) * I_) + q;
            hr[bi] = (const float4*)(hbase + (size_t)(b0 + bi) * hstride + hoff) + q;
        }

#pragma unroll 2
        for (int i = 0; i < 8; ++i) {
            const int o = i * 16;
            const float4 w0 = wri[o], w1 = wzi[o], w2 = wni[o];
            const float4 w3 = wrh[o], w4 = wzh[o], w5 = wnh[o];
#pragma unroll
            for (int bi = 0; bi < 4; ++bi) {
                const float4 xv = xr[bi][o];
                const float4 hv = hr[bi][o];
                air[bi] = fmaf(w0.x, xv.x, fmaf(w0.y, xv.y, fmaf(w0.z, xv.z, fmaf(w0.w, xv.w, air[bi]))));
                aiz[bi] = fmaf(w1.x, xv.x, fmaf(w1.y, xv.y, fmaf(w1.z, xv.z, fmaf(w1.w, xv.w, aiz[bi]))));
                ain[bi] = fmaf(w2.x, xv.x, fmaf(w2.y, xv.y, fmaf(w2.z, xv.z, fmaf(w2.w, xv.w, ain[bi]))));
                ahr[bi] = fmaf(w3.x, hv.x, fmaf(w3.y, hv.y, fmaf(w3.z, hv.z, fmaf(w3.w, hv.w, ahr[bi]))));
                ahz[bi] = fmaf(w4.x, hv.x, fmaf(w4.y, hv.y, fmaf(w4.z, hv.z, fmaf(w4.w, hv.w, ahz[bi]))));
                ahn[bi] = fmaf(w5.x, hv.x, fmaf(w5.y, hv.y, fmaf(w5.z, hv.z, fmaf(w5.w, hv.w, ahn[bi]))));
            }
        }

        // reduce the K-partials across q (lane bits 0..3)
#pragma unroll
        for (int bi = 0; bi < 4; ++bi) {
            air[bi] += __shfl_xor(air[bi], 1); air[bi] += __shfl_xor(air[bi], 2);
            air[bi] += __shfl_xor(air[bi], 4); air[bi] += __shfl_xor(air[bi], 8);
            aiz[bi] += __shfl_xor(aiz[bi], 1); aiz[bi] += __shfl_xor(aiz[bi], 2);
            aiz[bi] += __shfl_xor(aiz[bi], 4); aiz[bi] += __shfl_xor(aiz[bi], 8);
            ain[bi] += __shfl_xor(ain[bi], 1); ain[bi] += __shfl_xor(ain[bi], 2);
            ain[bi] += __shfl_xor(ain[bi], 4); ain[bi] += __shfl_xor(ain[bi], 8);
            ahr[bi] += __shfl_xor(ahr[bi], 1); ahr[bi] += __shfl_xor(ahr[bi], 2);
            ahr[bi] += __shfl_xor(ahr[bi], 4); ahr[bi] += __shfl_xor(ahr[bi], 8);
            ahz[bi] += __shfl_xor(ahz[bi], 1); ahz[bi] += __shfl_xor(ahz[bi], 2);
            ahz[bi] += __shfl_xor(ahz[bi], 4); ahz[bi] += __shfl_xor(ahz[bi], 8);
            ahn[bi] += __shfl_xor(ahn[bi], 1); ahn[bi] += __shfl_xor(ahn[bi], 2);
            ahn[bi] += __shfl_xor(ahn[bi], 4); ahn[bi] += __shfl_xor(ahn[bi], 8);
        }

        // gate math (all lanes compute redundantly; q==0 writes)
        float hnew[4];
#pragma unroll
        for (int bi = 0; bi < 4; ++bi) {
            const float hp = hbase[(size_t)(b0 + bi) * hstride + hoff + j];
            const float r  = sigmoid_(air[bi] + bihr + ahr[bi] + bhhr);
            const float z  = sigmoid_(aiz[bi] + bihz + ahz[bi] + bhhz);
            const float n  = tanh_(ain[bi] + bihn + r * (ahn[bi] + bhhn));
            hnew[bi] = (1.0f - z) * n + z * hp;
        }
        if (q == 0) {
#pragma unroll
            for (int bi = 0; bi < 4; ++bi) {
                out[((size_t)t * B_ + (b0 + bi)) * (2 * H_) + d * H_ + j] = hnew[bi];
                if (k == T_ - 1)   // final hidden state -> hn region
                    out[(size_t)T_ * B_ * (2 * H_) + ((size_t)d * B_ + (b0 + bi)) * H_ + j] = hnew[bi];
            }
        }
        __threadfence();   // release h_t writes device-wide before the barrier
        grid.sync();
    }
}

extern "C" void kernel_launch(void* const* d_in, const int* in_sizes, int n_in,
                              void* d_out, int out_size, void* d_ws, size_t ws_size,
                              hipStream_t stream) {
    const float* x    = (const float*)d_in[0];
    const float* h0   = (const float*)d_in[1];
    const float* w_ih = (const float*)d_in[2];
    const float* w_hh = (const float*)d_in[3];
    const float* b_ih = (const float*)d_in[4];
    const float* b_hh = (const float*)d_in[5];
    float* out = (float*)d_out;

    void* args[] = { (void*)&x, (void*)&h0, (void*)&w_ih, (void*)&w_hh,
                     (void*)&b_ih, (void*)&b_hh, (void*)&out };
    const unsigned shmem = 24 * 512 * sizeof(float);   // 48 KiB
    hipLaunchCooperativeKernel((void*)gru_bidir, dim3(NBLK), dim3(NTHR),
                               args, shmem, stream);
}

// Round 2
// 8787.746 us; speedup vs baseline: 4.9929x; 4.9929x over previous
//
#include <hip/hip_runtime.h>

// T=512, B=32, I=512, H=512, bidirectional GRU, fp32.
// Persistent cooperative kernel. 256 blocks = 2 dirs x 128 slices
// (each slice owns 4 h-indices). 512 threads/block:
//   tid = [bgh(1) | jj(2) | bglow(2) | q(4)]
// h-state propagates through the output buffer y (y[t] IS h_t) at rotating
// addresses, written with agent-scope write-through stores (sc0 sc1 -> L3).
// Readers use normal cached vector loads: the lines are new every step, so
// no XCD can hold a stale copy -> no L2 writeback/invalidate needed at all.
// Sync = per-direction monotonic arrival counter in d_ws (one relaxed
// agent atomicAdd per block per step), NOT cg::grid.sync (whose per-thread
// agent fences cost ~86us/step in round 1: VALUBusy 4%, 42/44ms in sync).

constexpr int T_ = 512, B_ = 32, I_ = 512, H_ = 512;
constexpr int NBLK = 256;
constexpr int NTHR = 512;
constexpr int DIRBLK = 128;          // blocks per direction
constexpr int ROW_F4 = 128;          // 512 floats per LDS row

__device__ __forceinline__ float sigmoid_(float v) {
    return 1.0f / (1.0f + __expf(-v));
}
__device__ __forceinline__ float tanh_(float v) {
    v = fminf(fmaxf(v, -15.0f), 15.0f);
    float e = __expf(2.0f * v);
    return (e - 1.0f) / (e + 1.0f);
}

__global__ __launch_bounds__(NTHR, 1) void gru_bidir(
    const float* __restrict__ x, const float* __restrict__ h0,
    const float* __restrict__ w_ih, const float* __restrict__ w_hh,
    const float* __restrict__ b_ih, const float* __restrict__ b_hh,
    float* __restrict__ out, unsigned* __restrict__ bar)
{
    extern __shared__ float lds[];           // 24 rows x 512 floats = 48 KiB
    float4* lds4 = (float4*)lds;

    const int bid = blockIdx.x;
    const int d   = bid >> 7;                // 0=fwd, 1=bwd
    const int s   = bid & 127;               // h-slice: indices [4s, 4s+4)
    const int tid = threadIdx.x;

    // ---- stage the block's 24 weight rows into LDS (one-time) ----
    for (int idx = tid; idx < 24 * ROW_F4; idx += NTHR) {
        const int row = idx >> 7;
        const int f4p = idx & 127;
        const int m   = row >> 2, jjr = row & 3;
        const int g   = (m < 3) ? m : m - 3;
        const float* W = (m < 3) ? w_ih : w_hh;
        const float4* src =
            (const float4*)(W + ((size_t)d * (3 * H_) + g * H_ + s * 4 + jjr) * (size_t)I_);
        lds4[row * ROW_F4 + f4p] = src[f4p];
    }
    __syncthreads();

    const int q     = tid & 15;
    const int bglow = (tid >> 4) & 3;
    const int upper = tid >> 6;
    const int jj    = upper & 3;             // uniform within a wave
    const int bgh   = upper >> 2;
    const int b0    = bgh * 16 + bglow * 4;  // this thread's 4 batch rows
    const int j     = s * 4 + jj;            // output h-index

    const float bihr = b_ih[d * 1536 + j];
    const float bihz = b_ih[d * 1536 + 512 + j];
    const float bihn = b_ih[d * 1536 + 1024 + j];
    const float bhhr = b_hh[d * 1536 + j];
    const float bhhz = b_hh[d * 1536 + 512 + j];
    const float bhhn = b_hh[d * 1536 + 1024 + j];

    const float4* wri = lds4 + (0 * 4 + jj) * ROW_F4 + q;
    const float4* wzi = lds4 + (1 * 4 + jj) * ROW_F4 + q;
    const float4* wni = lds4 + (2 * 4 + jj) * ROW_F4 + q;
    const float4* wrh = lds4 + (3 * 4 + jj) * ROW_F4 + q;
    const float4* wzh = lds4 + (4 * 4 + jj) * ROW_F4 + q;
    const float4* wnh = lds4 + (5 * 4 + jj) * ROW_F4 + q;

    unsigned* ctr = bar + (d << 5);          // 128B apart per direction

    for (int k = 0; k < T_; ++k) {
        const int t = d ? (T_ - 1 - k) : k;
        const float* hbase;
        int hstride, hoff;
        if (k == 0) {
            hbase = h0 + (size_t)d * B_ * H_; hstride = H_; hoff = 0;
        } else {
            const int tp = d ? (t + 1) : (t - 1);
            hbase = out + (size_t)tp * B_ * (2 * H_); hstride = 2 * H_; hoff = d * H_;
        }

        float air[4], aiz[4], ain[4], ahr[4], ahz[4], ahn[4];
#pragma unroll
        for (int bi = 0; bi < 4; ++bi) {
            air[bi] = 0.f; aiz[bi] = 0.f; ain[bi] = 0.f;
            ahr[bi] = 0.f; ahz[bi] = 0.f; ahn[bi] = 0.f;
        }

        const float4* xr[4];
        const float4* hr[4];
#pragma unroll
        for (int bi = 0; bi < 4; ++bi) {
            xr[bi] = (const float4*)(x + ((size_t)t * B_ + (b0 + bi)) * I_) + q;
            hr[bi] = (const float4*)(hbase + (size_t)(b0 + bi) * hstride + hoff) + q;
        }

#pragma unroll 2
        for (int i = 0; i < 8; ++i) {
            const int o = i * 16;
            const float4 w0 = wri[o], w1 = wzi[o], w2 = wni[o];
            const float4 w3 = wrh[o], w4 = wzh[o], w5 = wnh[o];
#pragma unroll
            for (int bi = 0; bi < 4; ++bi) {
                const float4 xv = xr[bi][o];
                const float4 hv = hr[bi][o];
                air[bi] = fmaf(w0.x, xv.x, fmaf(w0.y, xv.y, fmaf(w0.z, xv.z, fmaf(w0.w, xv.w, air[bi]))));
                aiz[bi] = fmaf(w1.x, xv.x, fmaf(w1.y, xv.y, fmaf(w1.z, xv.z, fmaf(w1.w, xv.w, aiz[bi]))));
                ain[bi] = fmaf(w2.x, xv.x, fmaf(w2.y, xv.y, fmaf(w2.z, xv.z, fmaf(w2.w, xv.w, ain[bi]))));
                ahr[bi] = fmaf(w3.x, hv.x, fmaf(w3.y, hv.y, fmaf(w3.z, hv.z, fmaf(w3.w, hv.w, ahr[bi]))));
                ahz[bi] = fmaf(w4.x, hv.x, fmaf(w4.y, hv.y, fmaf(w4.z, hv.z, fmaf(w4.w, hv.w, ahz[bi]))));
                ahn[bi] = fmaf(w5.x, hv.x, fmaf(w5.y, hv.y, fmaf(w5.z, hv.z, fmaf(w5.w, hv.w, ahn[bi]))));
            }
        }

        // merge i+h partials for r,z (added anyway), reduce across q lanes
        float hnew[4];
#pragma unroll
        for (int bi = 0; bi < 4; ++bi) {
            float ar = air[bi] + ahr[bi];
            float az = aiz[bi] + ahz[bi];
            float an = ain[bi];
            float ah = ahn[bi];
#pragma unroll
            for (int m = 1; m < 16; m <<= 1) {
                ar += __shfl_xor(ar, m);
                az += __shfl_xor(az, m);
                an += __shfl_xor(an, m);
                ah += __shfl_xor(ah, m);
            }
            const float hp = hbase[(size_t)(b0 + bi) * hstride + hoff + j];
            const float r  = sigmoid_(ar + bihr + bhhr);
            const float z  = sigmoid_(az + bihz + bhhz);
            const float n  = tanh_(an + bihn + r * (ah + bhhn));
            hnew[bi] = (1.0f - z) * n + z * hp;
        }

        if (q == 0) {
#pragma unroll
            for (int bi = 0; bi < 4; ++bi) {
                // write-through to the shared L3 so other XCDs' loads see it
                __hip_atomic_store(
                    &out[((size_t)t * B_ + (b0 + bi)) * (2 * H_) + d * H_ + j],
                    hnew[bi], __ATOMIC_RELAXED, __HIP_MEMORY_SCOPE_AGENT);
                if (k == T_ - 1)
                    out[(size_t)T_ * B_ * (2 * H_) + ((size_t)d * B_ + (b0 + bi)) * H_ + j] = hnew[bi];
            }
        }

        if (k + 1 < T_) {
            // ---- lightweight per-direction barrier ----
            asm volatile("s_waitcnt vmcnt(0)" ::: "memory");  // h stores acked at L3
            __syncthreads();
            if (tid == 0) {
                __hip_atomic_fetch_add(ctr, 1u, __ATOMIC_RELAXED, __HIP_MEMORY_SCOPE_AGENT);
                const unsigned tgt = (unsigned)(k + 1) * DIRBLK;
                while (__hip_atomic_load(ctr, __ATOMIC_RELAXED, __HIP_MEMORY_SCOPE_AGENT) < tgt)
                    __builtin_amdgcn_s_sleep(1);
            }
            __syncthreads();
        }
    }
}

extern "C" void kernel_launch(void* const* d_in, const int* in_sizes, int n_in,
                              void* d_out, int out_size, void* d_ws, size_t ws_size,
                              hipStream_t stream) {
    const float* x    = (const float*)d_in[0];
    const float* h0   = (const float*)d_in[1];
    const float* w_ih = (const float*)d_in[2];
    const float* w_hh = (const float*)d_in[3];
    const float* b_ih = (const float*)d_in[4];
    const float* b_hh = (const float*)d_in[5];
    float* out = (float*)d_out;
    unsigned* bar = (unsigned*)d_ws;

    hipMemsetAsync(d_ws, 0, 256, stream);   // zero barrier counters (ws is poisoned)

    void* args[] = { (void*)&x, (void*)&h0, (void*)&w_ih, (void*)&w_hh,
                     (void*)&b_ih, (void*)&b_hh, (void*)&out, (void*)&bar };
    const unsigned shmem = 24 * 512 * sizeof(float);   // 48 KiB
    hipLaunchCooperativeKernel((void*)gru_bidir, dim3(NBLK), dim3(NTHR),
                               args, shmem, stream);
}

// Round 4
// 3847.608 us; speedup vs baseline: 11.4034x; 2.2840x over previous
//
#include <hip/hip_runtime.h>

// T=512, B=32, I=512, H=512, bidirectional GRU, fp32.
// Persistent kernel, 256 blocks = 2 dirs x 128 slices (4 h-indices each),
// 512 threads: tid = [bgh(1) | jj(2) | bglow(2) | q(4)].
// h_t lives in the output buffer y (rotating addresses), published with
// write-through dwordx4 stores (sc0 sc1 -> L3); readers use normal cached
// loads (lines are new every step -> no stale-L2 hazard).
// Sync = per-block monotonic step-flags (own 64B line each, NO atomics/RMW):
//   producer: vmcnt(0) after h stores, then flag[s] = k+1 (write-through)
//   consumer: wave 0 polls all 128 flags of its direction (2 loads/lane)
// The x-matvec partials for step k+1 are computed between flag-publish and
// poll, hiding the sync round-trip under independent compute.
// Round-2 postmortem: counting barrier (same-line atomicAdd x128 + 2 L3
// round-trips + 128 scattered scalar store-acks) cost ~13.8us/step.
// Round-3 fix: HIP float4 is a struct -> inline asm "v" rejects it; use
// ext_vector_type(4) float for the dwordx4 store operand.

constexpr int T_ = 512, B_ = 32, I_ = 512, H_ = 512;
constexpr int NBLK = 256;
constexpr int NTHR = 512;
constexpr int ROW_F4 = 128;          // 512 floats per LDS weight row
constexpr int FLAG_STRIDE = 16;      // dwords; 64B per flag line

typedef float f32x4 __attribute__((ext_vector_type(4)));

__device__ __forceinline__ float sigmoid_(float v) {
    return 1.0f / (1.0f + __expf(-v));
}
__device__ __forceinline__ float tanh_(float v) {
    v = fminf(fmaxf(v, -15.0f), 15.0f);
    float e = __expf(2.0f * v);
    return (e - 1.0f) / (e + 1.0f);
}

__global__ __launch_bounds__(NTHR, 1) void gru_bidir(
    const float* __restrict__ x, const float* __restrict__ h0,
    const float* __restrict__ w_ih, const float* __restrict__ w_hh,
    const float* __restrict__ b_ih, const float* __restrict__ b_hh,
    float* __restrict__ out, unsigned* __restrict__ flags)
{
    extern __shared__ float lds[];           // 24x512 weights + 128 gather
    float4* lds4 = (float4*)lds;
    float*  ldsh = lds + 24 * 512;           // h gather buffer (128 floats)

    const int bid = blockIdx.x;
    const int d   = bid >> 7;                // 0=fwd, 1=bwd
    const int s   = bid & 127;               // h-slice: indices [4s, 4s+4)
    const int tid = threadIdx.x;

    // ---- stage the block's 24 weight rows into LDS (one-time) ----
    for (int idx = tid; idx < 24 * ROW_F4; idx += NTHR) {
        const int row = idx >> 7;
        const int f4p = idx & 127;
        const int m   = row >> 2, jjr = row & 3;
        const int g   = (m < 3) ? m : m - 3;
        const float* W = (m < 3) ? w_ih : w_hh;
        const float4* src =
            (const float4*)(W + ((size_t)d * (3 * H_) + g * H_ + s * 4 + jjr) * (size_t)I_);
        lds4[row * ROW_F4 + f4p] = src[f4p];
    }
    __syncthreads();

    const int q     = tid & 15;
    const int bglow = (tid >> 4) & 3;
    const int upper = tid >> 6;
    const int jj    = upper & 3;             // uniform within a wave
    const int bgh   = upper >> 2;
    const int b0    = bgh * 16 + bglow * 4;  // this thread's 4 batch rows
    const int j     = s * 4 + jj;            // output h-index

    const float bihr = b_ih[d * 1536 + j];
    const float bihz = b_ih[d * 1536 + 512 + j];
    const float bihn = b_ih[d * 1536 + 1024 + j];
    const float bhhr = b_hh[d * 1536 + j];
    const float bhhz = b_hh[d * 1536 + 512 + j];
    const float bhhn = b_hh[d * 1536 + 1024 + j];

    const float4* wri = lds4 + (0 * 4 + jj) * ROW_F4 + q;
    const float4* wzi = lds4 + (1 * 4 + jj) * ROW_F4 + q;
    const float4* wni = lds4 + (2 * 4 + jj) * ROW_F4 + q;
    const float4* wrh = lds4 + (3 * 4 + jj) * ROW_F4 + q;
    const float4* wzh = lds4 + (4 * 4 + jj) * ROW_F4 + q;
    const float4* wnh = lds4 + (5 * 4 + jj) * ROW_F4 + q;

    unsigned* flagdir = flags + d * 128 * FLAG_STRIDE;

    // x-side partials (independent of h) — computed one step ahead
    float xar[4], xaz[4], xan[4];
    auto xpart = [&](int t) {
#pragma unroll
        for (int bi = 0; bi < 4; ++bi) { xar[bi] = 0.f; xaz[bi] = 0.f; xan[bi] = 0.f; }
        const float4* xr[4];
#pragma unroll
        for (int bi = 0; bi < 4; ++bi)
            xr[bi] = (const float4*)(x + ((size_t)t * B_ + (b0 + bi)) * I_) + q;
#pragma unroll 2
        for (int i = 0; i < 8; ++i) {
            const int o = i * 16;
            const float4 w0 = wri[o], w1 = wzi[o], w2 = wni[o];
#pragma unroll
            for (int bi = 0; bi < 4; ++bi) {
                const float4 xv = xr[bi][o];
                xar[bi] = fmaf(w0.x, xv.x, fmaf(w0.y, xv.y, fmaf(w0.z, xv.z, fmaf(w0.w, xv.w, xar[bi]))));
                xaz[bi] = fmaf(w1.x, xv.x, fmaf(w1.y, xv.y, fmaf(w1.z, xv.z, fmaf(w1.w, xv.w, xaz[bi]))));
                xan[bi] = fmaf(w2.x, xv.x, fmaf(w2.y, xv.y, fmaf(w2.z, xv.z, fmaf(w2.w, xv.w, xan[bi]))));
            }
        }
    };

    xpart(d ? T_ - 1 : 0);                   // prologue: step 0's x-partials

    for (int k = 0; k < T_; ++k) {
        const int t = d ? (T_ - 1 - k) : k;

        // ---- wait for h_{k-1}: poll all 128 producer flags of this dir ----
        if (k > 0 && tid < 64) {
            const unsigned tgt = (unsigned)k;
            unsigned* f0 = flagdir + tid * FLAG_STRIDE;
            unsigned* f1 = flagdir + (64 + tid) * FLAG_STRIDE;
            for (;;) {
                const unsigned a = __hip_atomic_load(f0, __ATOMIC_RELAXED, __HIP_MEMORY_SCOPE_AGENT);
                const unsigned b = __hip_atomic_load(f1, __ATOMIC_RELAXED, __HIP_MEMORY_SCOPE_AGENT);
                if (__all(a >= tgt && b >= tgt)) break;
                __builtin_amdgcn_s_sleep(1);
            }
        }
        __syncthreads();                     // A: h_{k-1} visible to all waves

        const float* hbase;
        int hstride, hoff;
        if (k == 0) {
            hbase = h0 + (size_t)d * B_ * H_; hstride = H_; hoff = 0;
        } else {
            const int tp = d ? (t + 1) : (t - 1);
            hbase = out + (size_t)tp * B_ * (2 * H_); hstride = 2 * H_; hoff = d * H_;
        }

        // prev-h scalars for the z-blend (issue early, cached loads)
        float hp[4];
#pragma unroll
        for (int bi = 0; bi < 4; ++bi)
            hp[bi] = hbase[(size_t)(b0 + bi) * hstride + hoff + j];

        // ---- h-side matvec ----
        float ahr[4], ahz[4], ahn[4];
#pragma unroll
        for (int bi = 0; bi < 4; ++bi) { ahr[bi] = 0.f; ahz[bi] = 0.f; ahn[bi] = 0.f; }
        const float4* hr[4];
#pragma unroll
        for (int bi = 0; bi < 4; ++bi)
            hr[bi] = (const float4*)(hbase + (size_t)(b0 + bi) * hstride + hoff) + q;
#pragma unroll 2
        for (int i = 0; i < 8; ++i) {
            const int o = i * 16;
            const float4 w3 = wrh[o], w4 = wzh[o], w5 = wnh[o];
#pragma unroll
            for (int bi = 0; bi < 4; ++bi) {
                const float4 hv = hr[bi][o];
                ahr[bi] = fmaf(w3.x, hv.x, fmaf(w3.y, hv.y, fmaf(w3.z, hv.z, fmaf(w3.w, hv.w, ahr[bi]))));
                ahz[bi] = fmaf(w4.x, hv.x, fmaf(w4.y, hv.y, fmaf(w4.z, hv.z, fmaf(w4.w, hv.w, ahz[bi]))));
                ahn[bi] = fmaf(w5.x, hv.x, fmaf(w5.y, hv.y, fmaf(w5.z, hv.z, fmaf(w5.w, hv.w, ahn[bi]))));
            }
        }

        // ---- reduce across q lanes, gates ----
#pragma unroll
        for (int bi = 0; bi < 4; ++bi) {
            float ar = xar[bi] + ahr[bi];
            float az = xaz[bi] + ahz[bi];
            float an = xan[bi];
            float ah = ahn[bi];
#pragma unroll
            for (int m = 1; m < 16; m <<= 1) {
                ar += __shfl_xor(ar, m);
                az += __shfl_xor(az, m);
                an += __shfl_xor(an, m);
                ah += __shfl_xor(ah, m);
            }
            const float r = sigmoid_(ar + bihr + bhhr);
            const float z = sigmoid_(az + bihz + bhhz);
            const float n = tanh_(an + bihn + r * (ah + bhhn));
            const float hnew = (1.0f - z) * n + z * hp[bi];
            if (q == 0) ldsh[(b0 + bi) * 4 + jj] = hnew;
        }
        __syncthreads();                     // B: gather buffer complete

        // ---- wave 0 publishes h_k: 32 coalesced write-through dwordx4 ----
        if (tid < 64) {
            if (tid < 32) {
                const f32x4 hv4 = *(const f32x4*)&ldsh[tid * 4];
                float* dst = out + ((size_t)t * B_ + tid) * (2 * H_) + d * H_ + s * 4;
                asm volatile("global_store_dwordx4 %0, %1, off sc0 sc1"
                             :: "v"(dst), "v"(hv4) : "memory");
                if (k == T_ - 1) {
                    float* hn = out + (size_t)T_ * B_ * (2 * H_)
                              + ((size_t)d * B_ + tid) * H_ + s * 4;
                    *(f32x4*)hn = hv4;
                }
            }
            asm volatile("s_waitcnt vmcnt(0)" ::: "memory");  // stores acked at L3
            if (tid == 0)
                __hip_atomic_store(flagdir + s * FLAG_STRIDE, (unsigned)(k + 1),
                                   __ATOMIC_RELAXED, __HIP_MEMORY_SCOPE_AGENT);
        }

        // ---- hide the sync round-trip: next step's x-partials ----
        if (k + 1 < T_) xpart(d ? (T_ - 2 - k) : (k + 1));
    }
}

extern "C" void kernel_launch(void* const* d_in, const int* in_sizes, int n_in,
                              void* d_out, int out_size, void* d_ws, size_t ws_size,
                              hipStream_t stream) {
    const float* x    = (const float*)d_in[0];
    const float* h0   = (const float*)d_in[1];
    const float* w_ih = (const float*)d_in[2];
    const float* w_hh = (const float*)d_in[3];
    const float* b_ih = (const float*)d_in[4];
    const float* b_hh = (const float*)d_in[5];
    float* out = (float*)d_out;
    unsigned* flags = (unsigned*)d_ws;

    // zero the 2 x 128 step-flags (64B apart); ws is re-poisoned every launch
    (void)hipMemsetAsync(d_ws, 0, 2 * 128 * FLAG_STRIDE * sizeof(unsigned), stream);

    void* args[] = { (void*)&x, (void*)&h0, (void*)&w_ih, (void*)&w_hh,
                     (void*)&b_ih, (void*)&b_hh, (void*)&out, (void*)&flags };
    const unsigned shmem = (24 * 512 + 128) * sizeof(float);   // 48.5 KiB
    (void)hipLaunchCooperativeKernel((void*)gru_bidir, dim3(NBLK), dim3(NTHR),
                                     args, shmem, stream);
}